// Round 26
// baseline (76.049 us; speedup 1.0000x reference)
//
#include <hip/hip_runtime.h>
#include <math.h>

// CapsNet dynamic routing, all-MFMA (16x16x32), hi/lo split packed into K.
//   x: [512,1152,8] f32, w: [10,1152,16,8] f32, out: [512,10,16] f32
// R26 = R25 bodies exact; p2 NS2 16->24 (NT=48, 6 stages): 768 blocks = 3/CU
//   (LDS 40KB permits 4/CU; lb(256,2) is only a regalloc floor). Inter-block
//   overlap on each CU hides the per-stage barrier drain.
// p1: NS1=24, lb(256,3) (R25). p0/reduce unchanged; truncation hi/lo split (R24).
// Partials -> P[ns][b][160]; reduce_squash sums + squashes.

#define BB   512
#define NN1  1152
#define CD   160
#define XB   (NN1*8)           // 9216
#define WELEM (10*NN1*16*8)    // 1474560

typedef __attribute__((ext_vector_type(8))) short bf16x8;
typedef __attribute__((ext_vector_type(4))) float f32x4;

#define MFMA32(a, b, c) __builtin_amdgcn_mfma_f32_16x16x32_bf16(a, b, c, 0, 0, 0)
#define ZERO4 ((f32x4){0.f, 0.f, 0.f, 0.f})

// truncation-split helpers (R24): hi = f's top 16 bits; lo = trunc-bf16(f - hi)
__device__ __forceinline__ void cvt_hilo8(f32x4 a, f32x4 b, bf16x8& h, bf16x8& l) {
#pragma unroll
    for (int i = 0; i < 4; ++i) {
        unsigned ua = __builtin_bit_cast(unsigned, a[i]);
        float hfa = __builtin_bit_cast(float, ua & 0xFFFF0000u);
        h[i] = (short)(ua >> 16);
        l[i] = (short)(__builtin_bit_cast(unsigned, a[i] - hfa) >> 16);
        unsigned ub = __builtin_bit_cast(unsigned, b[i]);
        float hfb = __builtin_bit_cast(float, ub & 0xFFFF0000u);
        h[4 + i] = (short)(ub >> 16);
        l[4 + i] = (short)(__builtin_bit_cast(unsigned, b[i] - hfb) >> 16);
    }
}
__device__ __forceinline__ int opaque_zero() {
    int z;
    asm volatile("v_mov_b32 %0, 0" : "=v"(z));
    return z;
}
__device__ __forceinline__ void load_lds16(const short* gp, char* lp) {
    __builtin_amdgcn_global_load_lds(
        (const __attribute__((address_space(1))) void*)gp,
        (__attribute__((address_space(3))) void*)lp, 16, 0, 0);
}
// stage 8 n's of w hi/lo into a 40KB buffer (hi segs c*2+q at 0, lo at 20480)
__device__ __forceinline__ void stage8(const short* wnh, const short* wnl,
                                       char* buf, int n0, int wv, int lane)
{
    const short* gsrc = (wv < 2) ? wnh : wnl;
    char* ldst = buf + ((wv < 2) ? 0 : 20480);
    const int segbase = (wv & 1) * 10;
#pragma unroll
    for (int j = 0; j < 10; ++j) {
        const int s = segbase + j;
        const short* gp = gsrc + ((size_t)((s >> 1) * NN1 + n0 + (s & 1) * 4)) * 128 + lane * 8;
        load_lds16(gp, ldst + s * 1024);
    }
}

// ---------------- p0: w -> wnat hi/lo (truncation split) ----------------
__global__ void p0(const float* __restrict__ w,
                   short* __restrict__ wnh, short* __restrict__ wnl)
{
    int i = blockIdx.x * 256 + threadIdx.x;      // 5760*256 == WELEM
    float f = w[i];
    unsigned u = __builtin_bit_cast(unsigned, f);
    float hf = __builtin_bit_cast(float, u & 0xFFFF0000u);
    wnh[i] = (short)(u >> 16);
    wnl[i] = (short)(__builtin_bit_cast(unsigned, f - hf) >> 16);
}

// ---------------- p1: s0 partials, mfma over (4n x 8k) ----------------
template<int NS>
__global__ __launch_bounds__(256, 3) void caps_p1(
    const float* __restrict__ x, const short* __restrict__ wnh, const short* __restrict__ wnl,
    float* __restrict__ P)
{
    constexpr int NT = NN1 / NS;
    constexpr int QPW = NT / 16;
    static_assert(NT % 16 == 0, "balanced quads");
    __shared__ float red[2][2560];

    const int ns = blockIdx.x, bt = blockIdx.y;
    const int tid = threadIdx.x, lane = tid & 63, wv = tid >> 6;
    const int lo = lane & 15, g = lane >> 4;
    const int btile = bt * 16;

    f32x4 acc[10];
#pragma unroll
    for (int c = 0; c < 10; ++c) acc[c] = ZERO4;

#pragma unroll 2
    for (int it = 0; it < QPW; ++it) {
        const int n0 = ns * NT + (wv * QPW + it) * 4;
        const float* px = x + (size_t)(btile + lo) * XB + (size_t)(n0 + g) * 8;
        f32x4 x0 = *(const f32x4*)px;
        f32x4 x1 = *(const f32x4*)(px + 4);
        bf16x8 ah, al;
        cvt_hilo8(x0, x1, ah, al);
#pragma unroll
        for (int c = 0; c < 10; ++c) {
            size_t off = (((size_t)c * NN1 + n0 + g) * 16 + lo) * 8;
            bf16x8 bh = *(const bf16x8*)(wnh + off);
            bf16x8 bl = *(const bf16x8*)(wnl + off);
            acc[c] = MFMA32(ah, bh, acc[c]);
            acc[c] = MFMA32(al, bh, acc[c]);
            acc[c] = MFMA32(ah, bl, acc[c]);
        }
    }

    if (wv == 1 || wv == 3) {
        float* s = red[wv >> 1];
#pragma unroll
        for (int c = 0; c < 10; ++c)
#pragma unroll
            for (int e = 0; e < 4; ++e) s[c * 256 + (g * 4 + e) * 16 + lo] = acc[c][e];
    }
    __syncthreads();
    if (wv == 0) {
#pragma unroll
        for (int c = 0; c < 10; ++c)
#pragma unroll
            for (int e = 0; e < 4; ++e) acc[c][e] += red[0][c * 256 + (g * 4 + e) * 16 + lo];
    } else if (wv == 2) {
#pragma unroll
        for (int c = 0; c < 10; ++c)
#pragma unroll
            for (int e = 0; e < 4; ++e) {
                int idx = c * 256 + (g * 4 + e) * 16 + lo;
                red[1][idx] += acc[c][e];
            }
    }
    __syncthreads();
    if (wv == 0) {
        float* dst = P + (size_t)ns * BB * CD;
#pragma unroll
        for (int c = 0; c < 10; ++c)
#pragma unroll
            for (int e = 0; e < 4; ++e)
                dst[(size_t)(btile + g * 4 + e) * CD + c * 16 + lo] =
                    acc[c][e] + red[1][c * 256 + (g * 4 + e) * 16 + lo];
    }
}

// ------- reduce over ns + squash(alpha*S) -------
__global__ void reduce_squash(const float* __restrict__ P, float* __restrict__ out,
                              int nsplit, float asq)
{
    int t = blockIdx.x * 256 + threadIdx.x;      // 320*256 == 81920
    float s = 0.f;
    const float* p = P + t;
    for (int ns = 0; ns < nsplit; ++ns, p += (size_t)BB * CD) s += *p;
    float sq = s * s;
#pragma unroll
    for (int m = 1; m < 16; m <<= 1) sq += __shfl_xor(sq, m, 64);
    float qq = asq * sq;
    float sc = qq / (1.f + qq) / sqrtf(sq);
    out[t] = s * sc;
}

// ---------------- p2: LDS-staged w, two-pass y, in-lane softmax ----------------
template<int NS>
__global__ __launch_bounds__(256, 2) void caps_p2(
    const float* __restrict__ x,
    const short* __restrict__ wnh, const short* __restrict__ wnl,
    const float* __restrict__ o0, float* __restrict__ P)
{
    constexpr int NT = NN1 / NS;
    constexpr int ITER = NT / 8;     // 8 n's staged per iteration
    static_assert(NT % 8 == 0, "8n per stage");

    __shared__ __align__(16) char lds[40960];    // hi at 0, lo at 20480; reused for reduce

    const int ns = blockIdx.x, bt = blockIdx.y;
    const int tid = threadIdx.x, lane = tid & 63, wv = tid >> 6;
    const int lo = lane & 15, g = lane >> 4;
    const int btile = bt * 16;
    const int b = btile + lo;

    const int ap_base = ((g == 1) ? 20480 : 0) + wv * 512 + lo * 16;   // n_loc = wv*2
    const int opq = opaque_zero();
    const float* po0 = o0 + (size_t)b * CD + g * 4;

    f32x4 acc[10];
#pragma unroll
    for (int c = 0; c < 10; ++c) acc[c] = ZERO4;

    const bf16x8 z8 = {0, 0, 0, 0, 0, 0, 0, 0};

    for (int it = 0; it < ITER; ++it) {
        const int n0 = ns * NT + it * 8;

        __syncthreads();
        stage8(wnh, wnl, lds, n0, wv, lane);
        __syncthreads();

        const int na = n0 + wv * 2;
        const float* px = x + (size_t)b * XB + (size_t)na * 8;
        f32x4 x0a = *(const f32x4*)px,       x0b = *(const f32x4*)(px + 4);
        f32x4 x1a = *(const f32x4*)(px + 8), x1b = *(const f32x4*)(px + 12);

        bf16x8 xh0, xl0, xh1, xl1;
        cvt_hilo8(x0a, x0b, xh0, xl0);
        cvt_hilo8(x1a, x1b, xh1, xl1);

        bf16x8 Bx0, Bx1;                         // [x_hi | x_hi | x_lo | 0] along K
        if (g == 3)      { Bx0 = z8;  Bx1 = z8;  }
        else if (g == 2) { Bx0 = xl0; Bx1 = xl1; }
        else             { Bx0 = xh0; Bx1 = xh1; }

        // ---- pass 1: y from LDS A-frags -> logit dot -> shfl d-reduce ----
        float L0[10], L1[10];
#pragma unroll
        for (int c = 0; c < 10; ++c) {
            bf16x8 A0 = *(const bf16x8*)(lds + ap_base + c * 2048);
            bf16x8 A1 = *(const bf16x8*)(lds + ap_base + c * 2048 + 256);
            f32x4 y0 = MFMA32(A0, Bx0, ZERO4);
            f32x4 y1 = MFMA32(A1, Bx1, ZERO4);
            f32x4 ov = *(const f32x4*)(po0 + c * 16);
            float lp0 = y0[0]*ov[0] + y0[1]*ov[1] + y0[2]*ov[2] + y0[3]*ov[3];
            float lp1 = y1[0]*ov[0] + y1[1]*ov[1] + y1[2]*ov[2] + y1[3]*ov[3];
            lp0 += __shfl_xor(lp0, 16, 64);
            lp0 += __shfl_xor(lp0, 32, 64);
            lp1 += __shfl_xor(lp1, 16, 64);
            lp1 += __shfl_xor(lp1, 32, 64);
            L0[c] = lp0;
            L1[c] = lp1;
        }

        // ---- softmax in-lane; raw exp (|L| < ~0.3) ----
        float d0 = 0.f, d1 = 0.f;
#pragma unroll
        for (int c = 0; c < 10; ++c) {
            L0[c] = __expf(L0[c]); d0 += L0[c];
            L1[c] = __expf(L1[c]); d1 += L1[c];
        }
        float i0 = 1.f / d0, i1 = 1.f / d1;

        // ---- pass 2: re-read LDS (laundered addr -> no CSE), acc += c1 * y ----
#pragma unroll
        for (int c = 0; c < 10; ++c) {
            bf16x8 A0 = *(const bf16x8*)(lds + opq + ap_base + c * 2048);
            bf16x8 A1 = *(const bf16x8*)(lds + opq + ap_base + c * 2048 + 256);
            f32x4 y0 = MFMA32(A0, Bx0, ZERO4);
            f32x4 y1 = MFMA32(A1, Bx1, ZERO4);
            float c0f = L0[c] * i0, c1f = L1[c] * i1;
#pragma unroll
            for (int e = 0; e < 4; ++e) acc[c][e] += c0f * y0[e] + c1f * y1[e];
        }
    }

    // 4-wave reduce, reusing lds
    __syncthreads();
    float* red0 = (float*)lds;
    float* red1 = (float*)(lds + 10240);
    if (wv == 1 || wv == 3) {
        float* s = (wv == 1) ? red0 : red1;
#pragma unroll
        for (int c = 0; c < 10; ++c)
#pragma unroll
            for (int e = 0; e < 4; ++e) s[c * 256 + (g * 4 + e) * 16 + lo] = acc[c][e];
    }
    __syncthreads();
    if (wv == 0) {
#pragma unroll
        for (int c = 0; c < 10; ++c)
#pragma unroll
            for (int e = 0; e < 4; ++e) acc[c][e] += red0[c * 256 + (g * 4 + e) * 16 + lo];
    } else if (wv == 2) {
#pragma unroll
        for (int c = 0; c < 10; ++c)
#pragma unroll
            for (int e = 0; e < 4; ++e) {
                int idx = c * 256 + (g * 4 + e) * 16 + lo;
                red1[idx] += acc[c][e];
            }
    }
    __syncthreads();
    if (wv == 0) {
        float* dst = P + (size_t)ns * BB * CD;
#pragma unroll
        for (int c = 0; c < 10; ++c)
#pragma unroll
            for (int e = 0; e < 4; ++e)
                dst[(size_t)(btile + lo) * CD + c * 16 + g * 4 + e] =
                    acc[c][e] + red1[c * 256 + (g * 4 + e) * 16 + lo];
    }
}

extern "C" void kernel_launch(void* const* d_in, const int* in_sizes, int n_in,
                              void* d_out, int out_size, void* d_ws, size_t ws_size,
                              hipStream_t stream)
{
    (void)in_sizes; (void)n_in; (void)out_size;
    const float* x = (const float*)d_in[0];
    const float* w = (const float*)d_in[1];
    float* out = (float*)d_out;

    char* base = (char*)d_ws;
    short* wnh = (short*)(base);
    short* wnl = (short*)(base + 2949120);
    float* o0  = (float*)(base + 5898240);
    float* P   = (float*)(base + 6225920);
    const size_t fixed = 6225920, slab = (size_t)BB * CD * sizeof(float);

    p0<<<WELEM / 256, 256, 0, stream>>>(w, wnh, wnl);

#define LAUNCH_NS(NS1, NS2)                                                            \
    do {                                                                               \
        caps_p1<NS1><<<dim3(NS1, 32), 256, 0, stream>>>(x, wnh, wnl, P);               \
        reduce_squash<<<320, 256, 0, stream>>>(P, o0, NS1, 0.01f);                     \
        caps_p2<NS2><<<dim3(NS2, 32), 256, 0, stream>>>(x, wnh, wnl, o0, P);           \
        reduce_squash<<<320, 256, 0, stream>>>(P, out, NS2, 1.0f);                     \
    } while (0)

    if      (ws_size >= fixed + slab * 24) LAUNCH_NS(24, 24);   // p1: 768 blk = 3/CU;
    else if (ws_size >= fixed + slab * 12) LAUNCH_NS(12, 12);   // p2: 768 blk = 3/CU (LDS allows 4)
    else                                   LAUNCH_NS(4, 4);
#undef LAUNCH_NS
}